// Round 5
// baseline (1607.957 us; speedup 1.0000x reference)
//
#include <hip/hip_runtime.h>
#include <hip/hip_bf16.h>

// B=256, L=2048, H=128, V=32000, THR=0.4, LN_EPS=1e-5. All fp32.
// Htab2 row (RS=136 floats, padded for LDS bank-disjointness):
//   [0:64)=h[0..63], [64:68)=pad, [68:132)=h[64..127], [132]=kk, [133]=inv.
// Scan v5b: rank-1 lookahead (v2 algebra) + v1/v4 barrier placement.
//   vp_{u+1} = vpb_{u+1} + g_u (k_u.k_{u+1}) e_u,  vpb computed one step early.
// Inter-barrier chain = red-read -> gate -> 2 FMA -> e^2 -> 4 DPP -> write.
// Update+matvec issued post-gate but consumed only after the NEXT barrier.
// 3 rotating k reg-buffers (k_u,k_{u+1},k_{u+2}); refill post-barrier, so the
// c-tree (ki_u*ki_{u+1}) needs no pre-barrier LDS read (v2's bug).
// 6-slot LDS ring, lead-4 DMA, vmcnt(4); DMA token prefetched one step early.
// v5b hardening: extra __syncthreads() between init register loads and loop
// entry — step 0's DMA overwrites slot 0, which init reads; all other slot
// reuses are barrier-separated, this one wasn't (race window once per block).

#define BB 256
#define LL 2048
#define HH 128
#define VV 32000
#define RS 136

typedef float f32x2 __attribute__((ext_vector_type(2)));

__device__ __forceinline__ void dma16(const float* g, float* l) {
  __builtin_amdgcn_global_load_lds(
      (const __attribute__((address_space(1))) void*)g,
      (__attribute__((address_space(3))) void*)l,
      16, 0, 0);
}

template <int CTRL>
__device__ __forceinline__ float dppadd(float x) {
  int y = __builtin_amdgcn_update_dpp(0, __float_as_int(x), CTRL, 0xF, 0xF, true);
  return x + __int_as_float(y);
}

// d = a*b + d  (packed 2x fp32)
__device__ __forceinline__ void pkfma(f32x2& d, f32x2 a, f32x2 b) {
  asm("v_pk_fma_f32 %0, %1, %2, %0" : "+v"(d) : "v"(a), "v"(b));
}

__device__ __forceinline__ void barrier_lgkm() {
  asm volatile("s_waitcnt lgkmcnt(0)\n\ts_barrier" ::: "memory");
}
__device__ __forceinline__ void wait_vmN(int n) {
  if (n == 5)      asm volatile("s_waitcnt vmcnt(5)" ::: "memory");
  else if (n == 4) asm volatile("s_waitcnt vmcnt(4)" ::: "memory");
  else if (n == 3) asm volatile("s_waitcnt vmcnt(3)" ::: "memory");
  else if (n == 2) asm volatile("s_waitcnt vmcnt(2)" ::: "memory");
  else if (n == 1) asm volatile("s_waitcnt vmcnt(1)" ::: "memory");
  else             asm volatile("s_waitcnt vmcnt(0)" ::: "memory");
}

// ---------------------------------------------------------------------------
// Kernel A: Htab2 row = LN(e + relu(e@W1+b1)@W2 + b2) (+ kk, inv), padded.
// (unchanged from verified baseline)
// ---------------------------------------------------------------------------
__global__ __launch_bounds__(256, 1) void build_htab_kernel(
    const float* __restrict__ embed,
    const float* __restrict__ W1,
    const float* __restrict__ b1,
    const float* __restrict__ W2,
    const float* __restrict__ b2,
    const float* __restrict__ gamma,
    const float* __restrict__ beta,
    float* __restrict__ Htab2)
{
  const int tid = threadIdx.x;
  const int j   = tid & 127;
  const int h2  = tid >> 7;

  float w1r[128];
#pragma unroll
  for (int m = 0; m < 128; ++m) w1r[m] = W1[m * 256 + tid];

  const float b1n = b1[tid];
  const float b2j = b2[j];
  const float gj  = gamma[j];
  const float bj  = beta[j];

  __shared__ __align__(16) float4 w2q[64][128];   // 128 KiB
  __shared__ __align__(16) float e_s[128];
  __shared__ __align__(16) float a_s[256];
  __shared__ float p_s[2][128];
  __shared__ float red[8];

  for (int idx = tid; idx < 8192; idx += 256) {
    int n4 = idx >> 7, jj = idx & 127;
    float4 w;
    w.x = W2[(size_t)(4 * n4 + 0) * 128 + jj];
    w.y = W2[(size_t)(4 * n4 + 1) * 128 + jj];
    w.z = W2[(size_t)(4 * n4 + 2) * 128 + jj];
    w.w = W2[(size_t)(4 * n4 + 3) * 128 + jj];
    w2q[n4][jj] = w;
  }
  __syncthreads();

  for (int v = blockIdx.x; v < VV; v += gridDim.x) {
    if (tid < 128) e_s[tid] = embed[(size_t)v * 128 + tid];
    __syncthreads();

    float acc[4] = {b1n, 0.f, 0.f, 0.f};
#pragma unroll
    for (int q = 0; q < 32; ++q) {
      float4 ev = *(const float4*)&e_s[4 * q];
      float t = ev.x * w1r[4 * q + 0];
      t = fmaf(ev.y, w1r[4 * q + 1], t);
      t = fmaf(ev.z, w1r[4 * q + 2], t);
      t = fmaf(ev.w, w1r[4 * q + 3], t);
      acc[q & 3] += t;
    }
    float a = fmaxf((acc[0] + acc[1]) + (acc[2] + acc[3]), 0.0f);
    a_s[tid] = a;
    __syncthreads();

    float p0 = 0.f, p1 = 0.f, p2v = 0.f, p3 = 0.f;
#pragma unroll
    for (int q = 0; q < 32; ++q) {
      int n4 = h2 * 32 + q;
      float4 av = *(const float4*)&a_s[4 * n4];
      float4 wq = w2q[n4][j];
      p0 = fmaf(av.x, wq.x, p0);
      p1 = fmaf(av.y, wq.y, p1);
      p2v = fmaf(av.z, wq.z, p2v);
      p3 = fmaf(av.w, wq.w, p3);
    }
    p_s[h2][j] = (p0 + p1) + (p2v + p3);
    __syncthreads();

    float y = 0.0f;
    if (tid < 128) {
      float ff = p_s[0][tid] + p_s[1][tid] + b2j;
      y = e_s[tid] + ff;
    }
    float s1 = y, s2 = y * y;
    s1 = dppadd<0xB1>(s1);  s2 = dppadd<0xB1>(s2);
    s1 = dppadd<0x4E>(s1);  s2 = dppadd<0x4E>(s2);
    s1 = dppadd<0x141>(s1); s2 = dppadd<0x141>(s2);
    s1 = dppadd<0x140>(s1); s2 = dppadd<0x140>(s2);
    s1 = dppadd<0x142>(s1); s2 = dppadd<0x142>(s2);
    s1 = dppadd<0x143>(s1); s2 = dppadd<0x143>(s2);
    if (tid < 128 && (tid & 63) == 63) {
      red[tid >> 6] = s1;
      red[2 + (tid >> 6)] = s2;
    }
    __syncthreads();
    float mu = (red[0] + red[1]) * (1.0f / 128.0f);
    float ms = (red[2] + red[3]) * (1.0f / 128.0f);
    float var = ms - mu * mu;
    float hv = 0.0f;
    if (tid < 128) {
      float dy = y - mu;
      hv = dy * (1.0f / sqrtf(var + 1e-5f)) * gj + bj;
      int ofs = tid + ((tid >> 6) << 2);           // padded layout
      Htab2[(size_t)v * RS + ofs] = hv;
    }
    float q2 = hv * hv;
    q2 = dppadd<0xB1>(q2);
    q2 = dppadd<0x4E>(q2);
    q2 = dppadd<0x141>(q2);
    q2 = dppadd<0x140>(q2);
    q2 = dppadd<0x142>(q2);
    q2 = dppadd<0x143>(q2);
    if (tid < 128 && (tid & 63) == 63) red[4 + (tid >> 6)] = q2;
    __syncthreads();
    if (tid == 0) {
      float kk = red[4] + red[5];
      Htab2[(size_t)v * RS + 132] = kk;
      Htab2[(size_t)v * RS + 133] = 1.0f / (kk + 1e-6f);
    }
    __syncthreads();
  }
}

// ---------------------------------------------------------------------------
// Kernel B: per-batch scan, lookahead pipeline. 256 blocks x 512 threads.
// Thread (i=tid>>2, q=tid&3) owns M[i][32q..32q+32) as 16 f32x2.
// Invariants entering step u (pre-barrier):
//   B[u%3]=k_u regs, B[(u+1)%3]=k_{u+1} regs, e=e_u, vpb=vpb_{u+1}=M_{u-1}k_{u+1},
//   tk=seq[u+6], slot j%6 holds k_j, DMAs outstanding for k_{u+2}..k_{u+6}.
// Step u: [pre] dma k_{u+6}; trees(e_u^2, ki_u*ki_{u+1}); write; barrier.
//         [post] red read; vmcnt(4); refill B[(u+2)%3]<-k_{u+2}; gate_u;
//                vp_{u+1}=vpb+ce*e; e_{u+1}; M+=g e_u k_u; vpb_{u+2}=M k_{u+2}.
// ---------------------------------------------------------------------------
__global__ __launch_bounds__(512, 1) void scan_kernel(
    const int* __restrict__ seq,
    const float* __restrict__ Htab2,
    const float* __restrict__ Wrp,
    const float* __restrict__ brp,
    float* __restrict__ rr)
{
  const int b     = blockIdx.x;
  const int tid   = threadIdx.x;
  const int i     = tid >> 2;              // row 0..127
  const int q     = tid & 3;               // column quarter
  const int lane  = tid & 63;
  const int wv    = tid >> 6;              // wave 0..7
  const int iofs  = i + ((i >> 6) << 2);   // padded-row index of h[i]
  const int kbase = (q & 1) * 32 + (q >> 1) * 68;  // float offset of own 32 cols

  __shared__ int seq_s[LL];
  __shared__ __align__(16) float slots[6][RS];
  __shared__ __align__(16) float2 red2[3][8];   // {||e||^2, c} per wave
  __shared__ __align__(16) float r_s[128];
  __shared__ float p2_s[4][128];

  // prologue DMAs: k0..k5 -> slots 0..5 (every wave issues its own copy)
  {
    for (int jj = 0; jj < 6; ++jj) {
      int tj = seq[(size_t)b * LL + jj];
      if (lane < 34)
        dma16(Htab2 + (size_t)tj * RS + lane * 4, &slots[jj][0]);
    }
  }
  for (int t = tid; t < LL; t += 512) seq_s[t] = seq[(size_t)b * LL + t];
  __syncthreads();   // full drain (incl. prologue DMAs) — once, at start

  f32x2 M2[16];
#pragma unroll
  for (int m = 0; m < 16; ++m) M2[m] = f32x2{0.f, 0.f};

  f32x2 kA[16], kB[16], kC[16];
  float kiA, kkA, invA, kiB, kkB, invB;
  float kiC = 0.f, kkC = 0.f, invC = 0.f;
  {
    const float4* kp = (const float4*)&slots[0][kbase];
#pragma unroll
    for (int m = 0; m < 8; ++m) {
      float4 tq = kp[m];
      kA[2 * m]     = f32x2{tq.x, tq.y};
      kA[2 * m + 1] = f32x2{tq.z, tq.w};
    }
    kiA = slots[0][iofs];
    float2 kv = *(const float2*)&slots[0][132];
    kkA = kv.x; invA = kv.y;
  }
  {
    const float4* kp = (const float4*)&slots[1][kbase];
#pragma unroll
    for (int m = 0; m < 8; ++m) {
      float4 tq = kp[m];
      kB[2 * m]     = f32x2{tq.x, tq.y};
      kB[2 * m + 1] = f32x2{tq.z, tq.w};
    }
    kiB = slots[1][iofs];
    float2 kv = *(const float2*)&slots[1][132];
    kkB = kv.x; invB = kv.y;
  }
#pragma unroll
  for (int m = 0; m < 16; ++m) kC[m] = f32x2{0.f, 0.f};

  // v5b: init reads of slots 0/1 must complete in ALL waves before any wave's
  // step-0 DMA (which overwrites slot 0) can land. One extra barrier, once.
  __syncthreads();

  // pipeline state
  float e   = kiA;     // e_0 = k_0 (vp_0 = 0)
  float vpb = 0.f;     // vpb_1 = M_{-1} k_1 = 0
  int   tk  = seq_s[6];

  // flags: do_issue (DMA k_{u+6}), do_pref (tk <- seq_s[u+7]),
  //        do_refill (k_{u+2} -> kr), do_tail (final: produce r only)
  auto step = [&](f32x2 (&kc)[16], float ki_c, float kk_c, float inv_c,
                  f32x2 (&kn)[16], float ki_n, float kk_n, float inv_n,
                  f32x2 (&kr)[16], float& ki_r, float& kk_r, float& inv_r,
                  int u, int p, int sn, int sd, int nwait,
                  int do_issue, int do_pref, int do_refill, int do_tail) {
    if (do_issue) {
      if (lane < 34)
        dma16(Htab2 + (size_t)tk * RS + lane * 4, &slots[sd][0]);
    }
    // pre-barrier: interleaved 4-level trees (rows counted once; quad-repl.)
    float s  = e * e;
    float c1 = ki_c * ki_n;
    s = dppadd<0x141>(s);  c1 = dppadd<0x141>(c1);
    s = dppadd<0x140>(s);  c1 = dppadd<0x140>(c1);
    s = dppadd<0x142>(s);  c1 = dppadd<0x142>(c1);
    s = dppadd<0x143>(s);  c1 = dppadd<0x143>(c1);
    if (lane == 63) red2[p][wv] = float2{s, c1};
    barrier_lgkm();                        // lgkmcnt(0)+s_barrier, NO vmcnt drain

    const float4* rp = (const float4*)&red2[p][0];
    float4 ra = rp[0], rb = rp[1], rc = rp[2], rd = rp[3];
    if (do_refill) {
      wait_vmN(nwait);
      const float4* kp = (const float4*)&slots[sn][kbase];
#pragma unroll
      for (int m = 0; m < 8; ++m) {
        float4 tq = kp[m];
        kr[2 * m]     = f32x2{tq.x, tq.y};
        kr[2 * m + 1] = f32x2{tq.z, tq.w};
      }
      ki_r = slots[sn][iofs];
      float2 kv = *(const float2*)&slots[sn][132];
      kk_r = kv.x; inv_r = kv.y;
    }
    if (do_pref) tk = seq_s[u + 7];
    float ne2 = ((ra.x + ra.z) + (rb.x + rb.z)) + ((rc.x + rc.z) + (rd.x + rd.z));
    float cc  = ((ra.y + ra.w) + (rb.y + rb.w)) + ((rc.y + rc.w) + (rd.y + rd.w));
    int  g  = ne2 > 0.16f * kk_c;          // ||e|| > 0.4*||v||  (squared form)
    float ge = g ? e : 0.0f;
    float ce = g ? cc : 0.0f;
    float vp = fmaf(ce, e, vpb);           // vp_{u+1} = M_u k_{u+1} (1 FMA!)
    if (do_tail) { vpb = vp; return; }     // u=2046: vp_2047 = r
    e = fmaf(-vp, inv_n, ki_n);            // e_{u+1}
    // pending update M_{u-1} -> M_u  (off the inter-barrier chain)
    f32x2 gev{ge, ge};
#pragma unroll
    for (int m = 0; m < 16; ++m) pkfma(M2[m], gev, kc[m]);
    // big matvec: vpb_{u+2} = M_u k_{u+2} (kr) — consumed after NEXT barrier
    f32x2 a0{0.f,0.f}, a1{0.f,0.f}, a2{0.f,0.f}, a3{0.f,0.f};
#pragma unroll
    for (int m = 0; m < 4; ++m) {
      pkfma(a0, kr[4 * m + 0], M2[4 * m + 0]);
      pkfma(a1, kr[4 * m + 1], M2[4 * m + 1]);
      pkfma(a2, kr[4 * m + 2], M2[4 * m + 2]);
      pkfma(a3, kr[4 * m + 3], M2[4 * m + 3]);
    }
    float nv = ((a0.x + a0.y) + (a1.x + a1.y)) + ((a2.x + a2.y) + (a3.x + a3.y));
    nv = dppadd<0xB1>(nv);
    nv = dppadd<0x4E>(nv);                 // full row dot, quad-replicated
    vpb = nv;
  };

  // main loop u=0..2039 (2040 = 6*340); buffers period 3, slots period 6.
  for (int t = 0; t < 2040; t += 6) {
    step(kA, kiA, kkA, invA, kB, kiB, kkB, invB, kC, kiC, kkC, invC,
         t + 0, 0, 2, 0, 4, 1, 1, 1, 0);
    step(kB, kiB, kkB, invB, kC, kiC, kkC, invC, kA, kiA, kkA, invA,
         t + 1, 1, 3, 1, 4, 1, 1, 1, 0);
    step(kC, kiC, kkC, invC, kA, kiA, kkA, invA, kB, kiB, kkB, invB,
         t + 2, 2, 4, 2, 4, 1, 1, 1, 0);
    step(kA, kiA, kkA, invA, kB, kiB, kkB, invB, kC, kiC, kkC, invC,
         t + 3, 0, 5, 3, 4, 1, 1, 1, 0);
    step(kB, kiB, kkB, invB, kC, kiC, kkC, invC, kA, kiA, kkA, invA,
         t + 4, 1, 0, 4, 4, 1, 1, 1, 0);
    step(kC, kiC, kkC, invC, kA, kiA, kkA, invA, kB, kiB, kkB, invB,
         t + 5, 2, 1, 5, 4, 1, 1, 1, 0);
  }
  // tail: u=2040..2046 (last DMA issue at u=2041 for k_2047; drain vmcnt 4->0)
  step(kA, kiA, kkA, invA, kB, kiB, kkB, invB, kC, kiC, kkC, invC,
       2040, 0, 2, 0, 4, 1, 1, 1, 0);     // pref reads seq_s[2047] (last)
  step(kB, kiB, kkB, invB, kC, kiC, kkC, invC, kA, kiA, kkA, invA,
       2041, 1, 3, 1, 4, 1, 0, 1, 0);     // issue k_2047
  step(kC, kiC, kkC, invC, kA, kiA, kkA, invA, kB, kiB, kkB, invB,
       2042, 2, 4, 2, 3, 0, 0, 1, 0);
  step(kA, kiA, kkA, invA, kB, kiB, kkB, invB, kC, kiC, kkC, invC,
       2043, 0, 5, 3, 2, 0, 0, 1, 0);
  step(kB, kiB, kkB, invB, kC, kiC, kkC, invC, kA, kiA, kkA, invA,
       2044, 1, 0, 4, 1, 0, 0, 1, 0);     // refill kA <- k_2046
  step(kC, kiC, kkC, invC, kA, kiA, kkA, invA, kB, kiB, kkB, invB,
       2045, 2, 1, 5, 0, 0, 0, 1, 0);     // refill kB <- k_2047
  step(kA, kiA, kkA, invA, kB, kiB, kkB, invB, kC, kiC, kkC, invC,
       2046, 0, 2, 0, 0, 0, 0, 0, 1);     // FINAL: vpb = r = M_2046 k_2047

  // r_s
  if (q == 0) r_s[i] = vpb;
  __syncthreads();

  // rr[b,:] = r @ Wrp + brp  (512 threads: 4 row-groups of 32)
  const int j = tid & 127;
  const int g = tid >> 7;
  float pac[2] = {0.f, 0.f};
#pragma unroll
  for (int m = 0; m < 32; ++m) {
    pac[m & 1] = fmaf(r_s[g * 32 + m],
                      Wrp[(size_t)(g * 32 + m) * 128 + j], pac[m & 1]);
  }
  p2_s[g][j] = pac[0] + pac[1];
  __syncthreads();
  if (tid < 128) {
    rr[(size_t)b * 128 + tid] =
        p2_s[0][tid] + p2_s[1][tid] + p2_s[2][tid] + p2_s[3][tid] + brp[tid];
  }
}

// ---------------------------------------------------------------------------
// Kernel C: out[b,v] = rr[b,:] @ Wout[:,v] + bout[v]  (unchanged)
// ---------------------------------------------------------------------------
__global__ __launch_bounds__(256, 1) void out_kernel(
    const float* __restrict__ rr,
    const float* __restrict__ Wout,
    const float* __restrict__ bout,
    float* __restrict__ out)
{
  const int tid = threadIdx.x;
  const int v = blockIdx.x * 64 + (tid & 63);
  const int bg = tid >> 6;
  const int b0 = blockIdx.y * 64;

  __shared__ float4 rs4[64][32];
  for (int idx = tid; idx < 2048; idx += 256) {
    int bb = idx >> 5, q = idx & 31;
    rs4[bb][q] = ((const float4*)rr)[(size_t)(b0 + bb) * 32 + q];
  }
  __syncthreads();

  float acc[16];
#pragma unroll
  for (int m = 0; m < 16; ++m) acc[m] = 0.0f;

  for (int h4 = 0; h4 < 32; ++h4) {
    float w0 = Wout[(size_t)(4 * h4 + 0) * VV + v];
    float w1 = Wout[(size_t)(4 * h4 + 1) * VV + v];
    float w2 = Wout[(size_t)(4 * h4 + 2) * VV + v];
    float w3 = Wout[(size_t)(4 * h4 + 3) * VV + v];
#pragma unroll
    for (int m = 0; m < 16; ++m) {
      float4 rv = rs4[bg * 16 + m][h4];
      float t = rv.x * w0;
      t = fmaf(rv.y, w1, t);
      t = fmaf(rv.z, w2, t);
      t = fmaf(rv.w, w3, t);
      acc[m] += t;
    }
  }
  float bo = bout[v];
#pragma unroll
  for (int m = 0; m < 16; ++m) {
    out[(size_t)(b0 + bg * 16 + m) * VV + v] = acc[m] + bo;
  }
}

// ---------------------------------------------------------------------------
extern "C" void kernel_launch(void* const* d_in, const int* in_sizes, int n_in,
                              void* d_out, int out_size, void* d_ws, size_t ws_size,
                              hipStream_t stream)
{
  const int* seq      = (const int*)d_in[0];
  const float* embed  = (const float*)d_in[1];
  const float* W1     = (const float*)d_in[2];
  const float* b1     = (const float*)d_in[3];
  const float* W2     = (const float*)d_in[4];
  const float* b2     = (const float*)d_in[5];
  const float* gamma  = (const float*)d_in[6];
  const float* beta   = (const float*)d_in[7];
  const float* Wrp    = (const float*)d_in[8];
  const float* brp    = (const float*)d_in[9];
  const float* Wout   = (const float*)d_in[10];
  const float* bout   = (const float*)d_in[11];
  float* out          = (float*)d_out;

  char* ws = (char*)d_ws;
  float* Htab2 = (float*)ws;                         // 32000*136*4 = 17,408,000 B
  float* rr    = (float*)(ws + 17408000);            //    131,072 B

  hipLaunchKernelGGL(build_htab_kernel, dim3(256), dim3(256), 0, stream,
                     embed, W1, b1, W2, b2, gamma, beta, Htab2);
  hipLaunchKernelGGL(scan_kernel, dim3(BB), dim3(512), 0, stream,
                     seq, Htab2, Wrp, brp, rr);
  hipLaunchKernelGGL(out_kernel, dim3(VV / 64, 4), dim3(256), 0, stream,
                     rr, Wout, bout, out);
}